// Round 1
// 128.631 us; speedup vs baseline: 1.0570x; 1.0570x over previous
//
#include <hip/hip_runtime.h>
#include <hip/hip_bf16.h>

#if !__has_builtin(__builtin_amdgcn_cvt_pk_f32_fp8) || !__has_builtin(__builtin_amdgcn_cvt_pk_fp8_f32)
#include <hip/hip_fp8.h>
#endif

#define Bx 512
#define Lx 256
#define Dx 100
#define Kx 14
#define VROWS 50001        // vocab + padding row
#define NEG_ROWS 1280      // 20 * 64
#define TPB 512
#define NGRP 16            // 512 / 32

#define PAD8  128          // bytes per fp8 row (1 cache line)
#define RAW8  100          // compact fallback

typedef float floatx2 __attribute__((ext_vector_type(2)));

__device__ __forceinline__ float dot4(float4 a, float4 b) {
    return a.x * b.x + a.y * b.y + a.z * b.z + a.w * b.w;
}

__device__ __forceinline__ float4 fp8x4_dec(unsigned u) {
#if __has_builtin(__builtin_amdgcn_cvt_pk_f32_fp8)
    floatx2 lo = __builtin_amdgcn_cvt_pk_f32_fp8((int)u, false);
    floatx2 hi = __builtin_amdgcn_cvt_pk_f32_fp8((int)u, true);
    return make_float4(lo.x, lo.y, hi.x, hi.y);
#else
    __hip_fp8_e4m3 a, b, c, d;
    a.__x = (unsigned char)(u & 0xFF);
    b.__x = (unsigned char)((u >> 8) & 0xFF);
    c.__x = (unsigned char)((u >> 16) & 0xFF);
    d.__x = (unsigned char)((u >> 24) & 0xFF);
    return make_float4((float)a, (float)b, (float)c, (float)d);
#endif
}

__device__ __forceinline__ unsigned fp8x4_enc(float4 v) {
#if __has_builtin(__builtin_amdgcn_cvt_pk_fp8_f32)
    int p = 0;
    p = __builtin_amdgcn_cvt_pk_fp8_f32(v.x, v.y, p, false);
    p = __builtin_amdgcn_cvt_pk_fp8_f32(v.z, v.w, p, true);
    return (unsigned)p;
#else
    __hip_fp8_e4m3 a(v.x), b(v.y), c(v.z), d(v.w);
    return (unsigned)a.__x | ((unsigned)b.__x << 8) |
           ((unsigned)c.__x << 16) | ((unsigned)d.__x << 24);
#endif
}

// ---- fp32 table -> fp8 rows; zero acc[0..3]; block 0 computes reg -> acc[3] ----
__global__ __launch_bounds__(256) void convert_kernel(
    const float* __restrict__ table, unsigned char* __restrict__ tb8,
    const float* __restrict__ Wf, float* __restrict__ acc, int RS8, int padded)
{
    const int tid = threadIdx.x;
    const int gid = blockIdx.x * 256 + tid;
    if (gid < 4) acc[gid] = 0.0f;

    const int row = gid >> 5;          // 32 dword slots per row
    const int c   = gid & 31;
    if (row < VROWS) {
        if (c < 25) {
            const float4 v = *reinterpret_cast<const float4*>(
                table + (size_t)row * Dx + c * 4);
            *reinterpret_cast<unsigned*>(tb8 + (size_t)row * RS8 + c * 4) = fp8x4_enc(v);
        } else if (padded) {
            *reinterpret_cast<unsigned*>(tb8 + (size_t)row * RS8 + c * 4) = 0u;
        }
    }

    // reg = || n n^T - 1 ||_F, depends only on Wf -> compute once in block 0
    if (blockIdx.x == 0) {
        __shared__ float n_sh[Kx];
        __shared__ float r_sh[256];
        if (tid < Kx) {
            const float4* w4 = reinterpret_cast<const float4*>(Wf + (size_t)tid * Dx);
            float s = 0.f;
            #pragma unroll
            for (int i = 0; i < 25; ++i) { const float4 w = w4[i]; s += dot4(w, w); }
            n_sh[tid] = sqrtf(s);
        }
        __syncthreads();
        float vv = 0.f;
        if (tid < Kx * Kx) {
            const int i = tid / Kx;
            const int j = tid - i * Kx;
            const float x = n_sh[i] * n_sh[j] - 1.0f;
            vv = x * x;
        }
        r_sh[tid] = vv;
        __syncthreads();
        for (int s = 128; s > 0; s >>= 1) {
            if (tid < s) r_sh[tid] += r_sh[tid + s];
            __syncthreads();
        }
        if (tid == 0) acc[3] = sqrtf(r_sh[0]);
    }
}

// ---- one block per batch element: neg gather + attn + pt/rs + partials ----
// last block to finish writes the final loss (ticket in acc[2]).
__global__ __launch_bounds__(TPB) void fused_all(
    const int* __restrict__ pos_ids, const int* __restrict__ neg_ids,
    const unsigned char* __restrict__ tb8,
    const float* __restrict__ W_att, const float* __restrict__ Wk,
    const float* __restrict__ bk, const float* __restrict__ Wf,
    const float* __restrict__ bf, float* __restrict__ pt_out,
    float* __restrict__ rs_out, float* __restrict__ acc,
    float* __restrict__ out, int RS8)
{
    const int tid  = threadIdx.x;
    const int grp  = tid >> 5;      // 0..15
    const int lane = tid & 31;      // 0..31
    const int b    = blockIdx.x;

    __shared__ __align__(16) unsigned rowbuf[Lx][26];   // fp8 pos rows, staged
    __shared__ int   ids[Lx];                           // pos byte-offsets (id*RS8)
    __shared__ int   idn[NEG_ROWS];                     // neg byte-offsets
    __shared__ __align__(16) float4 part4[NGRP][26];
    __shared__ __align__(16) float ys_sh[104];
    __shared__ __align__(16) float t_sh[104];
    __shared__ float zs_sh[104];
    __shared__ float pt_sh[Kx];
    __shared__ float m_sh[NGRP], s_sh[NGRP], sc_sh[NGRP];
    __shared__ float wred[8][2];

    float* pf = (float*)part4;      // [16][104] float view

    if (tid < Lx) ids[tid] = pos_ids[(size_t)b * Lx + tid] * RS8;
    for (int i = tid; i < NEG_ROWS; i += TPB)
        idn[i] = neg_ids[(size_t)b * NEG_ROWS + i] * RS8;
    __syncthreads();

    // ---- phase 1: neg gather (1280 rows), kept in registers until the end ----
    float4 na = {0.f, 0.f, 0.f, 0.f};
    if (lane < 25) {
        const int o = lane * 4;
        float4 a0 = {0,0,0,0}, a1 = {0,0,0,0}, a2 = {0,0,0,0}, a3 = {0,0,0,0};
        for (int r = grp; r < NEG_ROWS; r += 64) {
            const float4 v0 = fp8x4_dec(*(const unsigned*)(tb8 + (size_t)idn[r]      + o));
            const float4 v1 = fp8x4_dec(*(const unsigned*)(tb8 + (size_t)idn[r + 16] + o));
            const float4 v2 = fp8x4_dec(*(const unsigned*)(tb8 + (size_t)idn[r + 32] + o));
            const float4 v3 = fp8x4_dec(*(const unsigned*)(tb8 + (size_t)idn[r + 48] + o));
            a0.x += v0.x; a0.y += v0.y; a0.z += v0.z; a0.w += v0.w;
            a1.x += v1.x; a1.y += v1.y; a1.z += v1.z; a1.w += v1.w;
            a2.x += v2.x; a2.y += v2.y; a2.z += v2.z; a2.w += v2.w;
            a3.x += v3.x; a3.y += v3.y; a3.z += v3.z; a3.w += v3.w;
        }
        na.x = a0.x + a1.x + a2.x + a3.x;
        na.y = a0.y + a1.y + a2.y + a3.y;
        na.z = a0.z + a1.z + a2.z + a3.z;
        na.w = a0.w + a1.w + a2.w + a3.w;
    }

    // ---- phase 2 (pass A): gather pos rows once, stage fp8 to LDS, sum -> ys ----
    if (lane < 25) {
        const int o = lane * 4;
        float4 a0 = {0,0,0,0}, a1 = {0,0,0,0}, a2 = {0,0,0,0}, a3 = {0,0,0,0};
        for (int r = grp; r < Lx; r += 64) {
            const unsigned u0 = *(const unsigned*)(tb8 + (size_t)ids[r]      + o);
            const unsigned u1 = *(const unsigned*)(tb8 + (size_t)ids[r + 16] + o);
            const unsigned u2 = *(const unsigned*)(tb8 + (size_t)ids[r + 32] + o);
            const unsigned u3 = *(const unsigned*)(tb8 + (size_t)ids[r + 48] + o);
            rowbuf[r][lane]      = u0;
            rowbuf[r + 16][lane] = u1;
            rowbuf[r + 32][lane] = u2;
            rowbuf[r + 48][lane] = u3;
            const float4 v0 = fp8x4_dec(u0);
            const float4 v1 = fp8x4_dec(u1);
            const float4 v2 = fp8x4_dec(u2);
            const float4 v3 = fp8x4_dec(u3);
            a0.x += v0.x; a0.y += v0.y; a0.z += v0.z; a0.w += v0.w;
            a1.x += v1.x; a1.y += v1.y; a1.z += v1.z; a1.w += v1.w;
            a2.x += v2.x; a2.y += v2.y; a2.z += v2.z; a2.w += v2.w;
            a3.x += v3.x; a3.y += v3.y; a3.z += v3.z; a3.w += v3.w;
        }
        a0.x += a1.x + a2.x + a3.x; a0.y += a1.y + a2.y + a3.y;
        a0.z += a1.z + a2.z + a3.z; a0.w += a1.w + a2.w + a3.w;
        part4[grp][lane] = a0;
    }
    __syncthreads();
    if (tid < Dx) {
        float s = 0.f;
        #pragma unroll
        for (int g = 0; g < NGRP; ++g) s += pf[g * 104 + tid];
        ys_sh[tid] = s * (1.0f / Lx);
    }
    __syncthreads();

    // ---- t = W_att @ ys (float4 x 25) ----
    if (tid < Dx) {
        const float4* w4 = reinterpret_cast<const float4*>(W_att + (size_t)tid * Dx);
        const float4* y4 = reinterpret_cast<const float4*>(ys_sh);
        float s = 0.f;
        #pragma unroll
        for (int i = 0; i < 25; ++i) s += dot4(w4[i], y4[i]);
        t_sh[tid] = s;
    }
    __syncthreads();

    // ---- pass B: online softmax + zs, rows decoded from LDS ----
    {
        const float4 tl = (lane < 25) ? ((const float4*)t_sh)[lane]
                                      : make_float4(0.f, 0.f, 0.f, 0.f);
        float m = -1e30f, ssum = 0.f;
        float4 za = {0.f, 0.f, 0.f, 0.f};
        for (int r = grp; r < Lx; r += 32) {
            const int id0 = ids[r];
            const int id1 = ids[r + 16];
            float4 e0 = {0,0,0,0}, e1 = {0,0,0,0};
            if (lane < 25) {
                e0 = fp8x4_dec(rowbuf[r][lane]);
                e1 = fp8x4_dec(rowbuf[r + 16][lane]);
            }
            float d0 = dot4(e0, tl);
            float d1 = dot4(e1, tl);
            #pragma unroll
            for (int o = 16; o > 0; o >>= 1) {
                d0 += __shfl_xor(d0, o, 32);
                d1 += __shfl_xor(d1, o, 32);
            }
            const float f0 = (id0 != 0) ? d0 : -1e30f;
            const float f1 = (id1 != 0) ? d1 : -1e30f;
            const float mn = fmaxf(m, fmaxf(f0, f1));
            const float sc = expf(m - mn);
            const float w0 = (id0 != 0) ? expf(d0 - mn) : 0.f;
            const float w1 = (id1 != 0) ? expf(d1 - mn) : 0.f;
            ssum = ssum * sc + w0 + w1;
            za.x = za.x * sc + w0 * e0.x + w1 * e1.x;
            za.y = za.y * sc + w0 * e0.y + w1 * e1.y;
            za.z = za.z * sc + w0 * e0.z + w1 * e1.z;
            za.w = za.w * sc + w0 * e0.w + w1 * e1.w;
            m = mn;
        }
        if (lane == 0) { m_sh[grp] = m; s_sh[grp] = ssum; }
        if (lane < 25) part4[grp][lane] = za;
    }
    __syncthreads();
    if (tid < NGRP) {
        float M = -1e30f;
        #pragma unroll
        for (int g = 0; g < NGRP; ++g) M = fmaxf(M, m_sh[g]);
        sc_sh[tid] = expf(m_sh[tid] - M);
    }
    __syncthreads();
    if (tid < Dx) {
        float S = 0.f, z = 0.f;
        #pragma unroll
        for (int g = 0; g < NGRP; ++g) {
            S += s_sh[g] * sc_sh[g];
            z += pf[g * 104 + tid] * sc_sh[g];
        }
        zs_sh[tid] = z / S;
    }
    __syncthreads();

    // ---- pt = sigmoid(zs @ Wk + bk) ----
    if (tid < Kx) {
        float s = bk[tid];
        for (int d = 0; d < Dx; ++d) s += zs_sh[d] * Wk[d * Kx + tid];
        const float pk = 1.0f / (1.0f + expf(-s));
        pt_sh[tid] = pk;
        pt_out[(size_t)b * Kx + tid] = pk;
    }
    __syncthreads();

    // ---- rs = bf + pt @ Wf ; pos partial = rs.zs (rs kept in register) ----
    float posc = 0.f, negc = 0.f, rs_reg = 0.f;
    if (tid < Dx) {
        float r = bf[tid];
        #pragma unroll
        for (int k = 0; k < Kx; ++k) r += pt_sh[k] * Wf[k * Dx + tid];
        rs_out[(size_t)b * Dx + tid] = r;
        rs_reg = r;
        posc = r * zs_sh[tid];
    }

    // ---- neg partial: reduce na across groups, dot with rs ----
    if (lane < 25) part4[grp][lane] = na;   // pf reads all done (sync above)
    __syncthreads();
    if (tid < Dx) {
        float gsum = 0.f;
        #pragma unroll
        for (int g = 0; g < NGRP; ++g) gsum += pf[g * 104 + tid];
        negc = gsum * rs_reg;
    }

    // ---- block reduce both partials (wave shuffle + 8 wave sums) ----
    #pragma unroll
    for (int o = 32; o > 0; o >>= 1) {
        posc += __shfl_xor(posc, o);
        negc += __shfl_xor(negc, o);
    }
    const int wid = tid >> 6;
    if ((tid & 63) == 0) { wred[wid][0] = posc; wred[wid][1] = negc; }
    __syncthreads();

    if (tid == 0) {
        float P = 0.f, N = 0.f;
        #pragma unroll
        for (int w = 0; w < 8; ++w) { P += wred[w][0]; N += wred[w][1]; }
        atomicAdd(&acc[0], P);
        atomicAdd(&acc[1], N);
        __threadfence();
        const unsigned t = atomicAdd(reinterpret_cast<unsigned int*>(acc) + 2, 1u);
        if (t == (unsigned)(Bx - 1)) {
            // last block: all partials are globally visible (fence-before-ticket)
            const float pos = atomicAdd(&acc[0], 0.0f);
            const float neg = atomicAdd(&acc[1], 0.0f);
            const float reg = atomicAdd(&acc[3], 0.0f);   // from convert_kernel
            const float margin = 1.0f - neg * (1.0f / 64.0f) + pos;
            out[0] = fmaxf(margin, 0.0f) + reg;           // LAMBDA = 1.0
        }
    }
}

extern "C" void kernel_launch(void* const* d_in, const int* in_sizes, int n_in,
                              void* d_out, int out_size, void* d_ws, size_t ws_size,
                              hipStream_t stream) {
    const int*   pos_ids = (const int*)  d_in[0];
    const int*   neg_ids = (const int*)  d_in[1];
    const float* table   = (const float*)d_in[2];
    const float* W_att   = (const float*)d_in[3];
    const float* Wk      = (const float*)d_in[4];
    const float* bk      = (const float*)d_in[5];
    const float* Wf      = (const float*)d_in[6];
    const float* bf      = (const float*)d_in[7];

    float* out    = (float*)d_out;
    float* pt_out = out + 1;
    float* rs_out = out + 1 + (size_t)Bx * Kx;

    const size_t need_pad = (size_t)VROWS * PAD8 + 16 + 4 * sizeof(float);
    const int padded = (ws_size >= need_pad) ? 1 : 0;
    const int RS8 = padded ? PAD8 : RAW8;

    unsigned char* tb8 = (unsigned char*)d_ws;
    size_t acc_off = (size_t)VROWS * RS8;
    acc_off = (acc_off + 15) & ~(size_t)15;
    float* acc = (float*)((char*)d_ws + acc_off);

    const int nthreads = VROWS * 32;
    convert_kernel<<<(nthreads + 255) / 256, 256, 0, stream>>>(
        table, tb8, Wf, acc, RS8, padded);
    fused_all<<<Bx, TPB, 0, stream>>>(
        pos_ids, neg_ids, tb8, W_att, Wk, bk, Wf, bf,
        pt_out, rs_out, acc, out, RS8);
}

// Round 2
// 125.876 us; speedup vs baseline: 1.0801x; 1.0219x over previous
//
#include <hip/hip_runtime.h>
#include <hip/hip_bf16.h>

#if !__has_builtin(__builtin_amdgcn_cvt_pk_f32_fp8) || !__has_builtin(__builtin_amdgcn_cvt_pk_fp8_f32)
#include <hip/hip_fp8.h>
#endif

#define Bx 512
#define Lx 256
#define Dx 100
#define Kx 14
#define VROWS 50001        // vocab + padding row
#define NEG_ROWS 1280      // 20 * 64
#define TPB 512
#define NGRP 16            // 512 / 32

#define PAD8  128          // bytes per fp8 row (1 cache line)
#define RAW8  100          // compact fallback

typedef float floatx2 __attribute__((ext_vector_type(2)));

__device__ __forceinline__ float dot4(float4 a, float4 b) {
    return a.x * b.x + a.y * b.y + a.z * b.z + a.w * b.w;
}

__device__ __forceinline__ float4 fp8x4_dec(unsigned u) {
#if __has_builtin(__builtin_amdgcn_cvt_pk_f32_fp8)
    floatx2 lo = __builtin_amdgcn_cvt_pk_f32_fp8((int)u, false);
    floatx2 hi = __builtin_amdgcn_cvt_pk_f32_fp8((int)u, true);
    return make_float4(lo.x, lo.y, hi.x, hi.y);
#else
    __hip_fp8_e4m3 a, b, c, d;
    a.__x = (unsigned char)(u & 0xFF);
    b.__x = (unsigned char)((u >> 8) & 0xFF);
    c.__x = (unsigned char)((u >> 16) & 0xFF);
    d.__x = (unsigned char)((u >> 24) & 0xFF);
    return make_float4((float)a, (float)b, (float)c, (float)d);
#endif
}

__device__ __forceinline__ unsigned fp8x4_enc(float4 v) {
#if __has_builtin(__builtin_amdgcn_cvt_pk_fp8_f32)
    int p = 0;
    p = __builtin_amdgcn_cvt_pk_fp8_f32(v.x, v.y, p, false);
    p = __builtin_amdgcn_cvt_pk_fp8_f32(v.z, v.w, p, true);
    return (unsigned)p;
#else
    __hip_fp8_e4m3 a(v.x), b(v.y), c(v.z), d(v.w);
    return (unsigned)a.__x | ((unsigned)b.__x << 8) |
           ((unsigned)c.__x << 16) | ((unsigned)d.__x << 24);
#endif
}

// decode one 16-B line-quarter (16 fp8) and accumulate into 4 float4 col-accs
__device__ __forceinline__ void acc16(uint4 u, float4* A) {
    const float4 v0 = fp8x4_dec(u.x);
    const float4 v1 = fp8x4_dec(u.y);
    const float4 v2 = fp8x4_dec(u.z);
    const float4 v3 = fp8x4_dec(u.w);
    A[0].x += v0.x; A[0].y += v0.y; A[0].z += v0.z; A[0].w += v0.w;
    A[1].x += v1.x; A[1].y += v1.y; A[1].z += v1.z; A[1].w += v1.w;
    A[2].x += v2.x; A[2].y += v2.y; A[2].z += v2.z; A[2].w += v2.w;
    A[3].x += v3.x; A[3].y += v3.y; A[3].z += v3.z; A[3].w += v3.w;
}

// fold the 4 row-subsets (lane bits [4:3]) of a 32-lane group
__device__ __forceinline__ void fold4(float4* A) {
    #pragma unroll
    for (int k = 0; k < 4; ++k) {
        A[k].x += __shfl_xor(A[k].x, 8);
        A[k].y += __shfl_xor(A[k].y, 8);
        A[k].z += __shfl_xor(A[k].z, 8);
        A[k].w += __shfl_xor(A[k].w, 8);
    }
    #pragma unroll
    for (int k = 0; k < 4; ++k) {
        A[k].x += __shfl_xor(A[k].x, 16);
        A[k].y += __shfl_xor(A[k].y, 16);
        A[k].z += __shfl_xor(A[k].z, 16);
        A[k].w += __shfl_xor(A[k].w, 16);
    }
}

// ---- fp32 table -> fp8 rows; zero acc[0..3]; block 0 computes reg -> acc[3] ----
__global__ __launch_bounds__(256) void convert_kernel(
    const float* __restrict__ table, unsigned char* __restrict__ tb8,
    const float* __restrict__ Wf, float* __restrict__ acc, int RS8, int padded)
{
    const int tid = threadIdx.x;
    const int gid = blockIdx.x * 256 + tid;
    if (gid < 4) acc[gid] = 0.0f;

    const int row = gid >> 5;          // 32 dword slots per row
    const int c   = gid & 31;
    if (row < VROWS) {
        if (c < 25) {
            const float4 v = *reinterpret_cast<const float4*>(
                table + (size_t)row * Dx + c * 4);
            *reinterpret_cast<unsigned*>(tb8 + (size_t)row * RS8 + c * 4) = fp8x4_enc(v);
        } else if (padded) {
            *reinterpret_cast<unsigned*>(tb8 + (size_t)row * RS8 + c * 4) = 0u;
        }
    }

    // reg = || n n^T - 1 ||_F, depends only on Wf -> compute once in block 0
    if (blockIdx.x == 0) {
        __shared__ float n_sh[Kx];
        __shared__ float r_sh[256];
        if (tid < Kx) {
            const float4* w4 = reinterpret_cast<const float4*>(Wf + (size_t)tid * Dx);
            float s = 0.f;
            #pragma unroll
            for (int i = 0; i < 25; ++i) { const float4 w = w4[i]; s += dot4(w, w); }
            n_sh[tid] = sqrtf(s);
        }
        __syncthreads();
        float vv = 0.f;
        if (tid < Kx * Kx) {
            const int i = tid / Kx;
            const int j = tid - i * Kx;
            const float x = n_sh[i] * n_sh[j] - 1.0f;
            vv = x * x;
        }
        r_sh[tid] = vv;
        __syncthreads();
        for (int s = 128; s > 0; s >>= 1) {
            if (tid < s) r_sh[tid] += r_sh[tid + s];
            __syncthreads();
        }
        if (tid == 0) acc[3] = sqrtf(r_sh[0]);
    }
}

// ========== padded fast path: 8-lane x uint4 row gathers (4 rows/group/inst) ==========
__global__ __launch_bounds__(TPB) void fused_all_pad(
    const int* __restrict__ pos_ids, const int* __restrict__ neg_ids,
    const unsigned char* __restrict__ tb8,
    const float* __restrict__ W_att, const float* __restrict__ Wk,
    const float* __restrict__ bk, const float* __restrict__ Wf,
    const float* __restrict__ bf, float* __restrict__ pt_out,
    float* __restrict__ rs_out, float* __restrict__ acc,
    float* __restrict__ out)
{
    const int tid  = threadIdx.x;
    const int grp  = tid >> 5;      // 0..15
    const int lane = tid & 31;      // 0..31
    const int b    = blockIdx.x;

    __shared__ __align__(16) unsigned rowbuf[Lx][32];   // staged fp8 pos rows (full lines)
    __shared__ int   ids[Lx];                           // pos byte-offsets (id*128)
    __shared__ int   idn[NEG_ROWS];                     // neg byte-offsets
    __shared__ __align__(16) float pf2[NGRP][128];      // per-group col partials
    __shared__ __align__(16) float ys_sh[104];
    __shared__ __align__(16) float t_sh[104];
    __shared__ float zs_sh[104];
    __shared__ float pt_sh[Kx];
    __shared__ float m_sh[NGRP], s_sh[NGRP], sc_sh[NGRP];
    __shared__ float wred[8][2];

    if (tid < Lx) ids[tid] = pos_ids[(size_t)b * Lx + tid] << 7;   // *128
    for (int i = tid; i < NEG_ROWS; i += TPB)
        idn[i] = neg_ids[(size_t)b * NEG_ROWS + i] << 7;
    __syncthreads();

    const int j16  = (lane & 7) * 16;   // byte offset of this lane's 16-B chunk
    const int j4   = (lane & 7) * 4;    // dword offset of chunk
    const int rsub = lane >> 3;         // row subset 0..3 within group

    // ---- phase 1: neg gather (1280 rows), 4 rows/group/inst, ILP 4 ----
    float4 An[4] = {{0,0,0,0},{0,0,0,0},{0,0,0,0},{0,0,0,0}};
    #pragma unroll 2
    for (int it = 0; it < NEG_ROWS / 256; ++it) {
        const int base = it * 256 + grp * 16 + rsub;
        const uint4 u0 = *(const uint4*)(tb8 + (size_t)idn[base]      + j16);
        const uint4 u1 = *(const uint4*)(tb8 + (size_t)idn[base + 4]  + j16);
        const uint4 u2 = *(const uint4*)(tb8 + (size_t)idn[base + 8]  + j16);
        const uint4 u3 = *(const uint4*)(tb8 + (size_t)idn[base + 12] + j16);
        acc16(u0, An); acc16(u1, An); acc16(u2, An); acc16(u3, An);
    }

    // ---- phase 2 (pass A): gather pos rows once, stage full lines to LDS ----
    {
        const int base = grp * 16 + rsub;
        const uint4 u0 = *(const uint4*)(tb8 + (size_t)ids[base]      + j16);
        const uint4 u1 = *(const uint4*)(tb8 + (size_t)ids[base + 4]  + j16);
        const uint4 u2 = *(const uint4*)(tb8 + (size_t)ids[base + 8]  + j16);
        const uint4 u3 = *(const uint4*)(tb8 + (size_t)ids[base + 12] + j16);
        *(uint4*)&rowbuf[base][j4]      = u0;
        *(uint4*)&rowbuf[base + 4][j4]  = u1;
        *(uint4*)&rowbuf[base + 8][j4]  = u2;
        *(uint4*)&rowbuf[base + 12][j4] = u3;
        float4 Ap[4] = {{0,0,0,0},{0,0,0,0},{0,0,0,0},{0,0,0,0}};
        acc16(u0, Ap); acc16(u1, Ap); acc16(u2, Ap); acc16(u3, Ap);
        fold4(Ap);
        if (lane < 8) {
            *(float4*)&pf2[grp][16 * lane]      = Ap[0];
            *(float4*)&pf2[grp][16 * lane + 4]  = Ap[1];
            *(float4*)&pf2[grp][16 * lane + 8]  = Ap[2];
            *(float4*)&pf2[grp][16 * lane + 12] = Ap[3];
        }
    }
    __syncthreads();
    if (tid < Dx) {
        float s = 0.f;
        #pragma unroll
        for (int gg = 0; gg < NGRP; ++gg) s += pf2[gg][tid];
        ys_sh[tid] = s * (1.0f / Lx);
    }
    __syncthreads();

    // ---- t = W_att @ ys (float4 x 25) ----
    if (tid < Dx) {
        const float4* w4 = reinterpret_cast<const float4*>(W_att + (size_t)tid * Dx);
        const float4* y4 = reinterpret_cast<const float4*>(ys_sh);
        float s = 0.f;
        #pragma unroll
        for (int i = 0; i < 25; ++i) s += dot4(w4[i], y4[i]);
        t_sh[tid] = s;
    }
    __syncthreads();

    // ---- pass B: online softmax + zs, rows decoded from LDS ----
    {
        const float4 tl = (lane < 25) ? ((const float4*)t_sh)[lane]
                                      : make_float4(0.f, 0.f, 0.f, 0.f);
        float m = -1e30f, ssum = 0.f;
        float4 za = {0.f, 0.f, 0.f, 0.f};
        for (int r = grp; r < Lx; r += 32) {
            const int id0 = ids[r];
            const int id1 = ids[r + 16];
            float4 e0 = {0,0,0,0}, e1 = {0,0,0,0};
            if (lane < 25) {
                e0 = fp8x4_dec(rowbuf[r][lane]);
                e1 = fp8x4_dec(rowbuf[r + 16][lane]);
            }
            float d0 = dot4(e0, tl);
            float d1 = dot4(e1, tl);
            #pragma unroll
            for (int o = 16; o > 0; o >>= 1) {
                d0 += __shfl_xor(d0, o, 32);
                d1 += __shfl_xor(d1, o, 32);
            }
            const float f0 = (id0 != 0) ? d0 : -1e30f;
            const float f1 = (id1 != 0) ? d1 : -1e30f;
            const float mn = fmaxf(m, fmaxf(f0, f1));
            const float sc = __expf(m - mn);
            const float w0 = (id0 != 0) ? __expf(d0 - mn) : 0.f;
            const float w1 = (id1 != 0) ? __expf(d1 - mn) : 0.f;
            ssum = ssum * sc + w0 + w1;
            za.x = za.x * sc + w0 * e0.x + w1 * e1.x;
            za.y = za.y * sc + w0 * e0.y + w1 * e1.y;
            za.z = za.z * sc + w0 * e0.z + w1 * e1.z;
            za.w = za.w * sc + w0 * e0.w + w1 * e1.w;
            m = mn;
        }
        if (lane == 0) { m_sh[grp] = m; s_sh[grp] = ssum; }
        if (lane < 25) ((float4*)pf2[grp])[lane] = za;
    }
    __syncthreads();
    if (tid < NGRP) {
        float M = -1e30f;
        #pragma unroll
        for (int gg = 0; gg < NGRP; ++gg) M = fmaxf(M, m_sh[gg]);
        sc_sh[tid] = __expf(m_sh[tid] - M);
    }
    __syncthreads();
    if (tid < Dx) {
        float S = 0.f, z = 0.f;
        #pragma unroll
        for (int gg = 0; gg < NGRP; ++gg) {
            S += s_sh[gg] * sc_sh[gg];
            z += pf2[gg][tid] * sc_sh[gg];
        }
        zs_sh[tid] = z / S;
    }
    __syncthreads();

    // ---- pt = sigmoid(zs @ Wk + bk) ----
    if (tid < Kx) {
        float s = bk[tid];
        for (int d = 0; d < Dx; ++d) s += zs_sh[d] * Wk[d * Kx + tid];
        const float pk = 1.0f / (1.0f + __expf(-s));
        pt_sh[tid] = pk;
        pt_out[(size_t)b * Kx + tid] = pk;
    }
    __syncthreads();

    // ---- rs = bf + pt @ Wf ; pos partial = rs.zs (rs kept in register) ----
    float posc = 0.f, negc = 0.f, rs_reg = 0.f;
    if (tid < Dx) {
        float r = bf[tid];
        #pragma unroll
        for (int k = 0; k < Kx; ++k) r += pt_sh[k] * Wf[k * Dx + tid];
        rs_out[(size_t)b * Dx + tid] = r;
        rs_reg = r;
        posc = r * zs_sh[tid];
    }

    // ---- neg partial: fold An, write col partials, dot with rs ----
    fold4(An);
    if (lane < 8) {      // pf2 readers (zs phase) completed before pt barrier
        *(float4*)&pf2[grp][16 * lane]      = An[0];
        *(float4*)&pf2[grp][16 * lane + 4]  = An[1];
        *(float4*)&pf2[grp][16 * lane + 8]  = An[2];
        *(float4*)&pf2[grp][16 * lane + 12] = An[3];
    }
    __syncthreads();
    if (tid < Dx) {
        float gsum = 0.f;
        #pragma unroll
        for (int gg = 0; gg < NGRP; ++gg) gsum += pf2[gg][tid];
        negc = gsum * rs_reg;
    }

    // ---- block reduce both partials (wave shuffle + 8 wave sums) ----
    #pragma unroll
    for (int o = 32; o > 0; o >>= 1) {
        posc += __shfl_xor(posc, o);
        negc += __shfl_xor(negc, o);
    }
    const int wid = tid >> 6;
    if ((tid & 63) == 0) { wred[wid][0] = posc; wred[wid][1] = negc; }
    __syncthreads();

    if (tid == 0) {
        float P = 0.f, N = 0.f;
        #pragma unroll
        for (int w = 0; w < 8; ++w) { P += wred[w][0]; N += wred[w][1]; }
        atomicAdd(&acc[0], P);
        atomicAdd(&acc[1], N);
        __threadfence();
        const unsigned t = atomicAdd(reinterpret_cast<unsigned int*>(acc) + 2, 1u);
        if (t == (unsigned)(Bx - 1)) {
            const float pos = atomicAdd(&acc[0], 0.0f);
            const float neg = atomicAdd(&acc[1], 0.0f);
            const float reg = atomicAdd(&acc[3], 0.0f);   // from convert_kernel
            const float margin = 1.0f - neg * (1.0f / 64.0f) + pos;
            out[0] = fmaxf(margin, 0.0f) + reg;           // LAMBDA = 1.0
        }
    }
}

// ========== compact fallback (RS8 = 100): 25-lane dword gathers ==========
__global__ __launch_bounds__(TPB) void fused_all_compact(
    const int* __restrict__ pos_ids, const int* __restrict__ neg_ids,
    const unsigned char* __restrict__ tb8,
    const float* __restrict__ W_att, const float* __restrict__ Wk,
    const float* __restrict__ bk, const float* __restrict__ Wf,
    const float* __restrict__ bf, float* __restrict__ pt_out,
    float* __restrict__ rs_out, float* __restrict__ acc,
    float* __restrict__ out, int RS8)
{
    const int tid  = threadIdx.x;
    const int grp  = tid >> 5;
    const int lane = tid & 31;
    const int b    = blockIdx.x;

    __shared__ __align__(16) unsigned rowbuf[Lx][26];
    __shared__ int   ids[Lx];
    __shared__ int   idn[NEG_ROWS];
    __shared__ __align__(16) float4 part4[NGRP][26];
    __shared__ __align__(16) float ys_sh[104];
    __shared__ __align__(16) float t_sh[104];
    __shared__ float zs_sh[104];
    __shared__ float pt_sh[Kx];
    __shared__ float m_sh[NGRP], s_sh[NGRP], sc_sh[NGRP];
    __shared__ float wred[8][2];

    float* pf = (float*)part4;

    if (tid < Lx) ids[tid] = pos_ids[(size_t)b * Lx + tid] * RS8;
    for (int i = tid; i < NEG_ROWS; i += TPB)
        idn[i] = neg_ids[(size_t)b * NEG_ROWS + i] * RS8;
    __syncthreads();

    float4 na = {0.f, 0.f, 0.f, 0.f};
    if (lane < 25) {
        const int o = lane * 4;
        float4 a0 = {0,0,0,0}, a1 = {0,0,0,0}, a2 = {0,0,0,0}, a3 = {0,0,0,0};
        for (int r = grp; r < NEG_ROWS; r += 64) {
            const float4 v0 = fp8x4_dec(*(const unsigned*)(tb8 + (size_t)idn[r]      + o));
            const float4 v1 = fp8x4_dec(*(const unsigned*)(tb8 + (size_t)idn[r + 16] + o));
            const float4 v2 = fp8x4_dec(*(const unsigned*)(tb8 + (size_t)idn[r + 32] + o));
            const float4 v3 = fp8x4_dec(*(const unsigned*)(tb8 + (size_t)idn[r + 48] + o));
            a0.x += v0.x; a0.y += v0.y; a0.z += v0.z; a0.w += v0.w;
            a1.x += v1.x; a1.y += v1.y; a1.z += v1.z; a1.w += v1.w;
            a2.x += v2.x; a2.y += v2.y; a2.z += v2.z; a2.w += v2.w;
            a3.x += v3.x; a3.y += v3.y; a3.z += v3.z; a3.w += v3.w;
        }
        na.x = a0.x + a1.x + a2.x + a3.x;
        na.y = a0.y + a1.y + a2.y + a3.y;
        na.z = a0.z + a1.z + a2.z + a3.z;
        na.w = a0.w + a1.w + a2.w + a3.w;
    }

    if (lane < 25) {
        const int o = lane * 4;
        float4 a0 = {0,0,0,0}, a1 = {0,0,0,0}, a2 = {0,0,0,0}, a3 = {0,0,0,0};
        for (int r = grp; r < Lx; r += 64) {
            const unsigned u0 = *(const unsigned*)(tb8 + (size_t)ids[r]      + o);
            const unsigned u1 = *(const unsigned*)(tb8 + (size_t)ids[r + 16] + o);
            const unsigned u2 = *(const unsigned*)(tb8 + (size_t)ids[r + 32] + o);
            const unsigned u3 = *(const unsigned*)(tb8 + (size_t)ids[r + 48] + o);
            rowbuf[r][lane]      = u0;
            rowbuf[r + 16][lane] = u1;
            rowbuf[r + 32][lane] = u2;
            rowbuf[r + 48][lane] = u3;
            const float4 v0 = fp8x4_dec(u0);
            const float4 v1 = fp8x4_dec(u1);
            const float4 v2 = fp8x4_dec(u2);
            const float4 v3 = fp8x4_dec(u3);
            a0.x += v0.x; a0.y += v0.y; a0.z += v0.z; a0.w += v0.w;
            a1.x += v1.x; a1.y += v1.y; a1.z += v1.z; a1.w += v1.w;
            a2.x += v2.x; a2.y += v2.y; a2.z += v2.z; a2.w += v2.w;
            a3.x += v3.x; a3.y += v3.y; a3.z += v3.z; a3.w += v3.w;
        }
        a0.x += a1.x + a2.x + a3.x; a0.y += a1.y + a2.y + a3.y;
        a0.z += a1.z + a2.z + a3.z; a0.w += a1.w + a2.w + a3.w;
        part4[grp][lane] = a0;
    }
    __syncthreads();
    if (tid < Dx) {
        float s = 0.f;
        #pragma unroll
        for (int gg = 0; gg < NGRP; ++gg) s += pf[gg * 104 + tid];
        ys_sh[tid] = s * (1.0f / Lx);
    }
    __syncthreads();

    if (tid < Dx) {
        const float4* w4 = reinterpret_cast<const float4*>(W_att + (size_t)tid * Dx);
        const float4* y4 = reinterpret_cast<const float4*>(ys_sh);
        float s = 0.f;
        #pragma unroll
        for (int i = 0; i < 25; ++i) s += dot4(w4[i], y4[i]);
        t_sh[tid] = s;
    }
    __syncthreads();

    {
        const float4 tl = (lane < 25) ? ((const float4*)t_sh)[lane]
                                      : make_float4(0.f, 0.f, 0.f, 0.f);
        float m = -1e30f, ssum = 0.f;
        float4 za = {0.f, 0.f, 0.f, 0.f};
        for (int r = grp; r < Lx; r += 32) {
            const int id0 = ids[r];
            const int id1 = ids[r + 16];
            float4 e0 = {0,0,0,0}, e1 = {0,0,0,0};
            if (lane < 25) {
                e0 = fp8x4_dec(rowbuf[r][lane]);
                e1 = fp8x4_dec(rowbuf[r + 16][lane]);
            }
            float d0 = dot4(e0, tl);
            float d1 = dot4(e1, tl);
            #pragma unroll
            for (int o = 16; o > 0; o >>= 1) {
                d0 += __shfl_xor(d0, o, 32);
                d1 += __shfl_xor(d1, o, 32);
            }
            const float f0 = (id0 != 0) ? d0 : -1e30f;
            const float f1 = (id1 != 0) ? d1 : -1e30f;
            const float mn = fmaxf(m, fmaxf(f0, f1));
            const float sc = __expf(m - mn);
            const float w0 = (id0 != 0) ? __expf(d0 - mn) : 0.f;
            const float w1 = (id1 != 0) ? __expf(d1 - mn) : 0.f;
            ssum = ssum * sc + w0 + w1;
            za.x = za.x * sc + w0 * e0.x + w1 * e1.x;
            za.y = za.y * sc + w0 * e0.y + w1 * e1.y;
            za.z = za.z * sc + w0 * e0.z + w1 * e1.z;
            za.w = za.w * sc + w0 * e0.w + w1 * e1.w;
            m = mn;
        }
        if (lane == 0) { m_sh[grp] = m; s_sh[grp] = ssum; }
        if (lane < 25) part4[grp][lane] = za;
    }
    __syncthreads();
    if (tid < NGRP) {
        float M = -1e30f;
        #pragma unroll
        for (int gg = 0; gg < NGRP; ++gg) M = fmaxf(M, m_sh[gg]);
        sc_sh[tid] = __expf(m_sh[tid] - M);
    }
    __syncthreads();
    if (tid < Dx) {
        float S = 0.f, z = 0.f;
        #pragma unroll
        for (int gg = 0; gg < NGRP; ++gg) {
            S += s_sh[gg] * sc_sh[gg];
            z += pf[gg * 104 + tid] * sc_sh[gg];
        }
        zs_sh[tid] = z / S;
    }
    __syncthreads();

    if (tid < Kx) {
        float s = bk[tid];
        for (int d = 0; d < Dx; ++d) s += zs_sh[d] * Wk[d * Kx + tid];
        const float pk = 1.0f / (1.0f + __expf(-s));
        pt_sh[tid] = pk;
        pt_out[(size_t)b * Kx + tid] = pk;
    }
    __syncthreads();

    float posc = 0.f, negc = 0.f, rs_reg = 0.f;
    if (tid < Dx) {
        float r = bf[tid];
        #pragma unroll
        for (int k = 0; k < Kx; ++k) r += pt_sh[k] * Wf[k * Dx + tid];
        rs_out[(size_t)b * Dx + tid] = r;
        rs_reg = r;
        posc = r * zs_sh[tid];
    }

    if (lane < 25) part4[grp][lane] = na;
    __syncthreads();
    if (tid < Dx) {
        float gsum = 0.f;
        #pragma unroll
        for (int gg = 0; gg < NGRP; ++gg) gsum += pf[gg * 104 + tid];
        negc = gsum * rs_reg;
    }

    #pragma unroll
    for (int o = 32; o > 0; o >>= 1) {
        posc += __shfl_xor(posc, o);
        negc += __shfl_xor(negc, o);
    }
    const int wid = tid >> 6;
    if ((tid & 63) == 0) { wred[wid][0] = posc; wred[wid][1] = negc; }
    __syncthreads();

    if (tid == 0) {
        float P = 0.f, N = 0.f;
        #pragma unroll
        for (int w = 0; w < 8; ++w) { P += wred[w][0]; N += wred[w][1]; }
        atomicAdd(&acc[0], P);
        atomicAdd(&acc[1], N);
        __threadfence();
        const unsigned t = atomicAdd(reinterpret_cast<unsigned int*>(acc) + 2, 1u);
        if (t == (unsigned)(Bx - 1)) {
            const float pos = atomicAdd(&acc[0], 0.0f);
            const float neg = atomicAdd(&acc[1], 0.0f);
            const float reg = atomicAdd(&acc[3], 0.0f);
            const float margin = 1.0f - neg * (1.0f / 64.0f) + pos;
            out[0] = fmaxf(margin, 0.0f) + reg;
        }
    }
}

extern "C" void kernel_launch(void* const* d_in, const int* in_sizes, int n_in,
                              void* d_out, int out_size, void* d_ws, size_t ws_size,
                              hipStream_t stream) {
    const int*   pos_ids = (const int*)  d_in[0];
    const int*   neg_ids = (const int*)  d_in[1];
    const float* table   = (const float*)d_in[2];
    const float* W_att   = (const float*)d_in[3];
    const float* Wk      = (const float*)d_in[4];
    const float* bk      = (const float*)d_in[5];
    const float* Wf      = (const float*)d_in[6];
    const float* bf      = (const float*)d_in[7];

    float* out    = (float*)d_out;
    float* pt_out = out + 1;
    float* rs_out = out + 1 + (size_t)Bx * Kx;

    const size_t need_pad = (size_t)VROWS * PAD8 + 16 + 4 * sizeof(float);
    const int padded = (ws_size >= need_pad) ? 1 : 0;
    const int RS8 = padded ? PAD8 : RAW8;

    unsigned char* tb8 = (unsigned char*)d_ws;
    size_t acc_off = (size_t)VROWS * RS8;
    acc_off = (acc_off + 15) & ~(size_t)15;
    float* acc = (float*)((char*)d_ws + acc_off);

    const int nthreads = VROWS * 32;
    convert_kernel<<<(nthreads + 255) / 256, 256, 0, stream>>>(
        table, tb8, Wf, acc, RS8, padded);
    if (padded) {
        fused_all_pad<<<Bx, TPB, 0, stream>>>(
            pos_ids, neg_ids, tb8, W_att, Wk, bk, Wf, bf,
            pt_out, rs_out, acc, out);
    } else {
        fused_all_compact<<<Bx, TPB, 0, stream>>>(
            pos_ids, neg_ids, tb8, W_att, Wk, bk, Wf, bf,
            pt_out, rs_out, acc, out, RS8);
    }
}